// Round 12
// baseline (517.706 us; speedup 1.0000x reference)
//
#include <hip/hip_runtime.h>
#include <hip/hip_fp8.h>
#include <stdint.h>

#define HID 64
#define INCH 128
#define NGRAPH 64
#define KEEPP 0.7f
#define SCAN_B 256   // elements per scan block

typedef __attribute__((ext_vector_type(8))) short short8;   // 8 bf16 = 4 VGPRs
typedef __attribute__((ext_vector_type(4))) float floatx4;  // MFMA acc
typedef __attribute__((ext_vector_type(2))) float floatx2;
typedef unsigned short ushort_t;

// ---------------- fp8 e4m3 (OCP) helpers — HW cvt on gfx950 ----------------
__device__ __forceinline__ uint8_t f2e4(float f) {
  __hip_fp8_e4m3 t(f);
  return (uint8_t)t.__x;
}
__device__ __forceinline__ float e42f(uint8_t b) {
  __hip_fp8_e4m3 t;
  t.__x = (__hip_fp8_storage_t)b;
  return (float)t;
}

// decode 4 packed fp8 (one dword) into 4 floats
__device__ __forceinline__ void e42f_x4(uint32_t r, float& f0, float& f1,
                                        float& f2, float& f3) {
#if __has_builtin(__builtin_amdgcn_cvt_pk_f32_fp8)
  floatx2 lo = __builtin_amdgcn_cvt_pk_f32_fp8((int)r, false);
  floatx2 hi = __builtin_amdgcn_cvt_pk_f32_fp8((int)r, true);
  f0 = lo.x; f1 = lo.y; f2 = hi.x; f3 = hi.y;
#else
  f0 = e42f((uint8_t)(r      ));
  f1 = e42f((uint8_t)(r >>  8));
  f2 = e42f((uint8_t)(r >> 16));
  f3 = e42f((uint8_t)(r >> 24));
#endif
}

// ---------------- Threefry-2x32 (JAX-compatible, 20 rounds) ----------------
__host__ __device__ inline void tf2x32(uint32_t k0, uint32_t k1,
                                       uint32_t& x0, uint32_t& x1) {
  const uint32_t ks2 = k0 ^ k1 ^ 0x1BD11BDAu;
#define ROTL32(v, d) (((v) << (d)) | ((v) >> (32 - (d))))
#define TF_RND(r) { x0 += x1; x1 = ROTL32(x1, r); x1 ^= x0; }
  x0 += k0; x1 += k1;
  TF_RND(13) TF_RND(15) TF_RND(26) TF_RND(6)
  x0 += k1;  x1 += ks2 + 1u;
  TF_RND(17) TF_RND(29) TF_RND(16) TF_RND(24)
  x0 += ks2; x1 += k0 + 2u;
  TF_RND(13) TF_RND(15) TF_RND(26) TF_RND(6)
  x0 += k0;  x1 += k1 + 3u;
  TF_RND(17) TF_RND(29) TF_RND(16) TF_RND(24)
  x0 += k1;  x1 += ks2 + 4u;
  TF_RND(13) TF_RND(15) TF_RND(26) TF_RND(6)
  x0 += ks2; x1 += k0 + 5u;
#undef TF_RND
#undef ROTL32
}

__device__ __forceinline__ bool keep_mask(uint32_t k0, uint32_t k1, uint32_t idx) {
  uint32_t x0 = 0u, x1 = idx;
  tf2x32(k0, k1, x0, x1);
  uint32_t bits = x0 ^ x1;
  float u = __uint_as_float((bits >> 9) | 0x3f800000u) - 1.0f;
  return u < KEEPP;
}

// ---------------- CSR build prelude ----------------
__global__ void k_hist(const int* __restrict__ dst, int E, int* __restrict__ counts) {
  int e = blockIdx.x * blockDim.x + threadIdx.x;
  if (e < E) atomicAdd(&counts[dst[e]], 1);
}

// ---- scan stage 1 + dinv + per-graph node counts (batch histogram) ----
__global__ __launch_bounds__(SCAN_B) void k_scan1d(const int* __restrict__ counts,
                                                   int* __restrict__ bsum,
                                                   float* __restrict__ dinv,
                                                   const int* __restrict__ batch,
                                                   float* __restrict__ cnts, int N) {
  __shared__ int lh[NGRAPH];
  if (threadIdx.x < NGRAPH) lh[threadIdx.x] = 0;
  __syncthreads();
  int i = blockIdx.x * SCAN_B + threadIdx.x;
  int v = 0;
  if (i < N) {
    v = counts[i];
    dinv[i] = rsqrtf((float)v + 1.0f);  // in-degree + self-loop
    atomicAdd(&lh[batch[i]], 1);
  }
  int r = v;
  for (int off = 32; off > 0; off >>= 1) r += __shfl_down(r, off);
  __shared__ int ws[4];
  if ((threadIdx.x & 63) == 0) ws[threadIdx.x >> 6] = r;
  __syncthreads();
  if (threadIdx.x == 0) bsum[blockIdx.x] = ws[0] + ws[1] + ws[2] + ws[3];
  if (threadIdx.x < NGRAPH && lh[threadIdx.x] != 0)
    atomicAdd(&cnts[threadIdx.x], (float)lh[threadIdx.x]);
}

// ---------------- W split helper (bf16 hi + residual lo, frag layout) ----------------
__device__ __forceinline__ void wsplit_one(const float* __restrict__ W,
                                           short8* __restrict__ Wh,
                                           short8* __restrict__ Wl, int i) {
  int lane = i & 63, f = i >> 6;
  int kc = f >> 2, ct = f & 3;
  int kbase = kc * 32 + ((lane >> 4) << 3);
  int n = ct * 16 + (lane & 15);
  short8 h, l;
#pragma unroll
  for (int j = 0; j < 8; ++j) {
    float w = W[(size_t)(kbase + j) * HID + n];
    uint32_t u = __float_as_uint(w);
    h[j] = (short)(u >> 16);
    float r = w - __uint_as_float(u & 0xFFFF0000u);
    l[j] = (short)(__float_as_uint(r) >> 16);
  }
  Wh[i] = h;
  Wl[i] = l;
}

// ---- scan stage 2 (block 0, + zero sums) + three W splits (blocks 1..3) ----
__global__ __launch_bounds__(1024) void k_scan2w(const int* __restrict__ bsum,
                                                 int* __restrict__ bpre, int B,
                                                 float* __restrict__ sums,
                                                 const float* __restrict__ W1,
                                                 short8* __restrict__ Wh1, short8* __restrict__ Wl1,
                                                 const float* __restrict__ W2,
                                                 short8* __restrict__ Wh2, short8* __restrict__ Wl2,
                                                 const float* __restrict__ W3,
                                                 short8* __restrict__ Wh3, short8* __restrict__ Wl3) {
  if (blockIdx.x == 0) {
    __shared__ int s[1024];
    int tid = threadIdx.x;
    for (int i = tid; i < NGRAPH * HID; i += 1024) sums[i] = 0.0f;
    int v = (tid < B) ? bsum[tid] : 0;
    s[tid] = v;
    __syncthreads();
    for (int off = 1; off < 1024; off <<= 1) {
      int t = (tid >= off) ? s[tid - off] : 0;
      __syncthreads();
      s[tid] += t;
      __syncthreads();
    }
    if (tid < B) bpre[tid] = s[tid] - v;  // exclusive
    return;
  }
  int b = blockIdx.x - 1;
  int tid = threadIdx.x;
  if (b == 0) {                      // W1: KC=4 -> 1024 entries
    wsplit_one(W1, Wh1, Wl1, tid);
  } else if (b == 1 && tid < 512) {  // W2: KC=2 -> 512 entries
    wsplit_one(W2, Wh2, Wl2, tid);
  } else if (b == 2 && tid < 512) {  // W3
    wsplit_one(W3, Wh3, Wl3, tid);
  }
}

// ---- scan stage 3: local scan + offset -> row_off, cursor ----
__global__ __launch_bounds__(SCAN_B) void k_scan3(const int* __restrict__ counts,
                                                  const int* __restrict__ bpre,
                                                  int* __restrict__ row_off,
                                                  int* __restrict__ cursor,
                                                  int N, int E) {
  __shared__ int s[SCAN_B];
  int tid = threadIdx.x;
  int i = blockIdx.x * SCAN_B + tid;
  int v = (i < N) ? counts[i] : 0;
  s[tid] = v;
  __syncthreads();
  for (int off = 1; off < SCAN_B; off <<= 1) {
    int t = (tid >= off) ? s[tid - off] : 0;
    __syncthreads();
    s[tid] += t;
    __syncthreads();
  }
  if (i < N) {
    int excl = bpre[blockIdx.x] + s[tid] - v;
    row_off[i] = excl;
    cursor[i] = excl;
  }
  if (i == 0) row_off[N] = E;
}

// ---------------- MFMA gemm tile body ----------------
template <int K>
__device__ __forceinline__ void mgemm_tile(const float* __restrict__ A,
                                           const short8* __restrict__ Wh,
                                           const short8* __restrict__ Wl,
                                           uint8_t* __restrict__ C, int N,
                                           int tile) {
  constexpr int KC = K / 32;
  const int lane = threadIdx.x & 63;
  const int wv = threadIdx.x >> 6;
  const int m = lane & 15;
  const int q = lane >> 4;
  const int row0 = tile * 64 + wv * 16;
  if (row0 >= N) return;
  const int arow = min(row0 + m, N - 1);
  const float* __restrict__ ap = A + (size_t)arow * K + (q << 3);

  floatx4 acc[4];
#pragma unroll
  for (int ct = 0; ct < 4; ++ct) acc[ct] = (floatx4){0.f, 0.f, 0.f, 0.f};

#pragma unroll
  for (int kc = 0; kc < KC; ++kc) {
    const floatx4* apv = (const floatx4*)(ap + kc * 32);
    floatx4 x0 = apv[0];
    floatx4 x1 = apv[1];
    short8 ah, al;
#pragma unroll
    for (int j = 0; j < 4; ++j) {
      uint32_t u = __float_as_uint(x0[j]);
      ah[j] = (short)(u >> 16);
      float r = x0[j] - __uint_as_float(u & 0xFFFF0000u);
      al[j] = (short)(__float_as_uint(r) >> 16);
    }
#pragma unroll
    for (int j = 0; j < 4; ++j) {
      uint32_t u = __float_as_uint(x1[j]);
      ah[4 + j] = (short)(u >> 16);
      float r = x1[j] - __uint_as_float(u & 0xFFFF0000u);
      al[4 + j] = (short)(__float_as_uint(r) >> 16);
    }
#pragma unroll
    for (int ct = 0; ct < 4; ++ct) {
      short8 bh = Wh[(kc * 4 + ct) * 64 + lane];
      short8 bl = Wl[(kc * 4 + ct) * 64 + lane];
      acc[ct] = __builtin_amdgcn_mfma_f32_16x16x32_bf16(ah, bh, acc[ct], 0, 0, 0);
      acc[ct] = __builtin_amdgcn_mfma_f32_16x16x32_bf16(ah, bl, acc[ct], 0, 0, 0);
      acc[ct] = __builtin_amdgcn_mfma_f32_16x16x32_bf16(al, bh, acc[ct], 0, 0, 0);
    }
  }

  uint8_t* __restrict__ cp = C + (size_t)row0 * HID;
#pragma unroll
  for (int ct = 0; ct < 4; ++ct)
#pragma unroll
    for (int r = 0; r < 4; ++r) {
      int rr = (q << 2) + r;
      if (row0 + rr < N) cp[(size_t)rr * HID + ct * 16 + m] = f2e4(acc[ct][r]);
    }
}

// ---------------- fused CSR build + MFMA GEMM layer 1 (interleaved) ----------------
template <int K>
__global__ __launch_bounds__(256) void k_mgemm_build(
    const float* __restrict__ A, const short8* __restrict__ Wh,
    const short8* __restrict__ Wl, uint8_t* __restrict__ C, int N,
    const int* __restrict__ src, const int* __restrict__ dst,
    const float* __restrict__ dinv, int* __restrict__ cursor,
    int2* __restrict__ csr, int E, int build_blocks, int gemm_blocks) {
  const long T = (long)build_blocks + gemm_blocks;
  const long b = (long)blockIdx.x;
  const long gb = (b * gemm_blocks) / T;
  const bool is_g = (((b + 1) * gemm_blocks) / T) != gb;
  if (!is_g) {
    int bb = (int)(b - gb);
    int e = bb * 256 + (int)threadIdx.x;
    if (e < E) {
      int s = src[e], d = dst[e];
      int pos = atomicAdd(&cursor[d], 1);
      csr[pos] = make_int2(s, __float_as_int(dinv[s] * dinv[d]));
    }
    return;
  }
  mgemm_tile<K>(A, Wh, Wl, C, N, (int)gb);
}

// ---------------- MFMA GEMM (standalone, layers 2/3) ----------------
template <int K>
__global__ __launch_bounds__(256) void k_mgemm(const float* __restrict__ A,
                                               const short8* __restrict__ Wh,
                                               const short8* __restrict__ Wl,
                                               uint8_t* __restrict__ C, int N) {
  mgemm_tile<K>(A, Wh, Wl, C, N, (int)blockIdx.x);
}

// ---------------- gather core: quarter-wave, packed fp8 decode ----------------
__device__ __forceinline__ float gather_core(const uint8_t* __restrict__ tmp,
                                             const int2* __restrict__ csr,
                                             int beg, int end, int q, int sl) {
  float a0 = 0.f, a1 = 0.f, a2 = 0.f, a3 = 0.f;
  for (int j = beg; j < end; j += 8) {
    int e0 = j + q, e1 = j + 4 + q;
    bool v0 = e0 < end, v1 = e1 < end;
    int2 p0 = csr[v0 ? e0 : beg];
    int2 p1 = csr[v1 ? e1 : beg];
    float w0 = v0 ? __int_as_float(p0.y) : 0.0f;
    float w1 = v1 ? __int_as_float(p1.y) : 0.0f;
    uint32_t r0 = *(const uint32_t*)(tmp + (size_t)p0.x * HID + sl * 4);
    uint32_t r1 = *(const uint32_t*)(tmp + (size_t)p1.x * HID + sl * 4);
    float f0, f1, f2, f3, g0, g1, g2, g3;
    e42f_x4(r0, f0, f1, f2, f3);
    e42f_x4(r1, g0, g1, g2, g3);
    a0 = fmaf(f0, w0, a0); a1 = fmaf(f1, w0, a1);
    a2 = fmaf(f2, w0, a2); a3 = fmaf(f3, w0, a3);
    a0 = fmaf(g0, w1, a0); a1 = fmaf(g1, w1, a1);
    a2 = fmaf(g2, w1, a2); a3 = fmaf(g3, w1, a3);
  }
  a0 += __shfl_xor(a0, 16); a0 += __shfl_xor(a0, 32);
  a1 += __shfl_xor(a1, 16); a1 += __shfl_xor(a1, 32);
  a2 += __shfl_xor(a2, 16); a2 += __shfl_xor(a2, 32);
  a3 += __shfl_xor(a3, 16); a3 += __shfl_xor(a3, 32);
  return (q == 0) ? a0 : (q == 1) ? a1 : (q == 2) ? a2 : a3;
}

// ---------------- gather + self-loop + bias + relu + dropout -> fp32 h ----------------
__global__ __launch_bounds__(256) void k_gather(const uint8_t* __restrict__ tmp,
                                                const int* __restrict__ row_off,
                                                const int2* __restrict__ csr,
                                                const float* __restrict__ dinv,
                                                const float* __restrict__ bias,
                                                float* __restrict__ outh, int N,
                                                uint32_t k0, uint32_t k1) {
  const int node = blockIdx.x * 4 + (threadIdx.x >> 6);
  const int lane = threadIdx.x & 63;
  const int q = lane >> 4;
  const int sl = lane & 15;
  if (node >= N) return;
  const int beg = __builtin_amdgcn_readfirstlane(row_off[node]);
  const int end = __builtin_amdgcn_readfirstlane(row_off[node + 1]);
  float acc = gather_core(tmp, csr, beg, end, q, sl);
  const int ch = sl * 4 + q;
  const float dnode = dinv[node];
  const int idx = node * HID + ch;
  float v = acc + e42f(tmp[(size_t)node * HID + ch]) * dnode * dnode + bias[ch];
  v = fmaxf(v, 0.0f);
  v = keep_mask(k0, k1, (uint32_t)idx) ? v / KEEPP : 0.0f;
  outh[idx] = v;
}

// ---------------- layer-3 gather fused with mean-pool accumulation ----------------
__global__ __launch_bounds__(256) void k_gather_pool(const uint8_t* __restrict__ tmp,
                                                     const int* __restrict__ row_off,
                                                     const int2* __restrict__ csr,
                                                     const float* __restrict__ dinv,
                                                     const float* __restrict__ bias,
                                                     const int* __restrict__ batch,
                                                     float* __restrict__ sums, int N,
                                                     uint32_t k0, uint32_t k1) {
  const int node = blockIdx.x * 4 + (threadIdx.x >> 6);
  const int lane = threadIdx.x & 63;
  const int q = lane >> 4;
  const int sl = lane & 15;
  if (node >= N) return;
  const int beg = __builtin_amdgcn_readfirstlane(row_off[node]);
  const int end = __builtin_amdgcn_readfirstlane(row_off[node + 1]);
  float acc = gather_core(tmp, csr, beg, end, q, sl);
  const int ch = sl * 4 + q;
  const float dnode = dinv[node];
  const int idx = node * HID + ch;
  float v = acc + e42f(tmp[(size_t)node * HID + ch]) * dnode * dnode + bias[ch];
  v = fmaxf(v, 0.0f);
  v = keep_mask(k0, k1, (uint32_t)idx) ? v / KEEPP : 0.0f;
  const int g = __builtin_amdgcn_readfirstlane(batch[node]);
  atomicAdd(&sums[g * HID + ch], v);
}

// ---------------- MLP head (single block) ----------------
__global__ __launch_bounds__(256) void k_head(const float* __restrict__ sums,
                                              const float* __restrict__ cnts,
                                              const float* __restrict__ Wm1,
                                              const float* __restrict__ bm1,
                                              const float* __restrict__ Wm2,
                                              const float* __restrict__ bm2,
                                              float* __restrict__ out,
                                              uint32_t k0, uint32_t k1) {
  __shared__ float pooled[NGRAPH * HID];
  __shared__ float m[NGRAPH * HID];
  for (int i = threadIdx.x; i < NGRAPH * HID; i += 256) {
    int g = i >> 6;
    pooled[i] = sums[i] / fmaxf(cnts[g], 1.0f);
  }
  __syncthreads();
  for (int i = threadIdx.x; i < NGRAPH * HID; i += 256) {
    int g = i >> 6, j = i & 63;
    float acc = bm1[j];
#pragma unroll 8
    for (int k = 0; k < HID; ++k)
      acc = fmaf(pooled[g * HID + k], Wm1[k * HID + j], acc);
    acc = fmaxf(acc, 0.0f);
    m[i] = keep_mask(k0, k1, (uint32_t)i) ? acc / KEEPP : 0.0f;
  }
  __syncthreads();
  if (threadIdx.x < NGRAPH) {
    int g = threadIdx.x;
    float acc = bm2[0];
#pragma unroll 8
    for (int j = 0; j < HID; ++j)
      acc = fmaf(m[g * HID + j], Wm2[j], acc);
    out[g] = acc;
  }
}

extern "C" void kernel_launch(void* const* d_in, const int* in_sizes, int n_in,
                              void* d_out, int out_size, void* d_ws, size_t ws_size,
                              hipStream_t stream) {
  const float* x     = (const float*)d_in[0];
  const int*   ei    = (const int*)d_in[1];
  const int*   batch = (const int*)d_in[2];
  const float* W1 = (const float*)d_in[3];
  const float* b1 = (const float*)d_in[4];
  const float* W2 = (const float*)d_in[5];
  const float* b2 = (const float*)d_in[6];
  const float* W3 = (const float*)d_in[7];
  const float* b3 = (const float*)d_in[8];
  const float* Wm1 = (const float*)d_in[9];
  const float* bm1 = (const float*)d_in[10];
  const float* Wm2 = (const float*)d_in[11];
  const float* bm2 = (const float*)d_in[12];
  float* out = (float*)d_out;

  const int N = in_sizes[0] / INCH;
  const int E = in_sizes[1] / 2;
  const int* src = ei;
  const int* dst = ei + E;
  const int NB = (N + SCAN_B - 1) / SCAN_B;

  // workspace layout (counts and cnts contiguous -> single memset)
  char* ws = (char*)d_ws;
  size_t off = 0;
  uint8_t* B0 = (uint8_t*)(ws + off); off += (size_t)N * HID;            // fp8 tmp
  off = (off + 15) & ~(size_t)15;
  float* B1      = (float*)(ws + off); off += (size_t)N * HID * 4;       // fp32 h
  int*   counts  = (int*)  (ws + off); off += (size_t)N * 4;
  float* cnts    = (float*)(ws + off); off += NGRAPH * 4;                // zeroed w/ counts
  float* dinv    = (float*)(ws + off); off += (size_t)N * 4;
  int*   row_off = (int*)  (ws + off); off += ((size_t)N + 4) * 4;
  int*   cursor  = (int*)  (ws + off); off += (size_t)N * 4;
  int*   bsum    = (int*)  (ws + off); off += 1024 * 4;
  int*   bpre    = (int*)  (ws + off); off += 1024 * 4;
  int2*  csr     = (int2*) (ws + off); off += (size_t)E * 8;
  float* sums    = (float*)(ws + off); off += NGRAPH * HID * 4;          // zeroed in scan2w
  off = (off + 15) & ~(size_t)15;
  short8* Wh1 = (short8*)(ws + off); off += 1024 * 16;
  short8* Wl1 = (short8*)(ws + off); off += 1024 * 16;
  short8* Wh2 = (short8*)(ws + off); off += 512 * 16;
  short8* Wl2 = (short8*)(ws + off); off += 512 * 16;
  short8* Wh3 = (short8*)(ws + off); off += 512 * 16;
  short8* Wl3 = (short8*)(ws + off); off += 512 * 16;

  // dropout keys: dk[i] = threefry2x32((0,42),(0,i))
  uint32_t dk[4][2];
  for (uint32_t i = 0; i < 4; ++i) {
    uint32_t a = 0u, b = i;
    tf2x32(0u, 42u, a, b);
    dk[i][0] = a; dk[i][1] = b;
  }

  // ---- prelude ----
  hipMemsetAsync(counts, 0, ((size_t)N + NGRAPH) * sizeof(int), stream);
  k_hist<<<(E + 255) / 256, 256, 0, stream>>>(dst, E, counts);
  k_scan1d<<<NB, SCAN_B, 0, stream>>>(counts, bsum, dinv, batch, cnts, N);
  k_scan2w<<<4, 1024, 0, stream>>>(bsum, bpre, NB, sums,
                                   W1, Wh1, Wl1, W2, Wh2, Wl2, W3, Wh3, Wl3);
  k_scan3<<<NB, SCAN_B, 0, stream>>>(counts, bpre, row_off, cursor, N, E);

  const int build_grid = (E + 255) / 256;
  const int mg_grid    = (N + 63) / 64;
  const int gath_grid  = (N + 3) / 4;

  // ---- layer 1 (K=128) GEMM fused with CSR build ----
  k_mgemm_build<INCH><<<build_grid + mg_grid, 256, 0, stream>>>(
      x, Wh1, Wl1, B0, N, src, dst, dinv, cursor, csr, E, build_grid, mg_grid);
  k_gather<<<gath_grid, 256, 0, stream>>>(B0, row_off, csr, dinv, b1,
                                          B1, N, dk[0][0], dk[0][1]);
  // ---- layer 2 (K=64) ----
  k_mgemm<HID><<<mg_grid, 256, 0, stream>>>(B1, Wh2, Wl2, B0, N);
  k_gather<<<gath_grid, 256, 0, stream>>>(B0, row_off, csr, dinv, b2,
                                          B1, N, dk[1][0], dk[1][1]);
  // ---- layer 3 (K=64) + fused mean-pool accumulation ----
  k_mgemm<HID><<<mg_grid, 256, 0, stream>>>(B1, Wh3, Wl3, B0, N);
  k_gather_pool<<<gath_grid, 256, 0, stream>>>(B0, row_off, csr, dinv, b3,
                                               batch, sums, N, dk[2][0], dk[2][1]);

  // ---- head ----
  k_head<<<1, 256, 0, stream>>>(sums, cnts, Wm1, bm1, Wm2, bm2, out,
                                dk[3][0], dk[3][1]);
  (void)n_in; (void)out_size; (void)ws_size;
}

// Round 13
// 411.554 us; speedup vs baseline: 1.2579x; 1.2579x over previous
//
#include <hip/hip_runtime.h>
#include <hip/hip_fp8.h>
#include <stdint.h>

#define HID 64
#define INCH 128
#define NGRAPH 64
#define KEEPP 0.7f
#define SCAN_B 256   // elements per scan block

typedef __attribute__((ext_vector_type(8))) short short8;   // 8 bf16 = 4 VGPRs
typedef __attribute__((ext_vector_type(4))) float floatx4;  // MFMA acc
typedef __attribute__((ext_vector_type(2))) float floatx2;
typedef unsigned short ushort_t;

// ---------------- fp8 e4m3 (OCP) helpers — HW cvt on gfx950 ----------------
__device__ __forceinline__ uint8_t f2e4(float f) {
  __hip_fp8_e4m3 t(f);
  return (uint8_t)t.__x;
}
__device__ __forceinline__ float e42f(uint8_t b) {
  __hip_fp8_e4m3 t;
  t.__x = (__hip_fp8_storage_t)b;
  return (float)t;
}

// decode 4 packed fp8 (one dword) into 4 floats
__device__ __forceinline__ void e42f_x4(uint32_t r, float& f0, float& f1,
                                        float& f2, float& f3) {
#if __has_builtin(__builtin_amdgcn_cvt_pk_f32_fp8)
  floatx2 lo = __builtin_amdgcn_cvt_pk_f32_fp8((int)r, false);
  floatx2 hi = __builtin_amdgcn_cvt_pk_f32_fp8((int)r, true);
  f0 = lo.x; f1 = lo.y; f2 = hi.x; f3 = hi.y;
#else
  f0 = e42f((uint8_t)(r      ));
  f1 = e42f((uint8_t)(r >>  8));
  f2 = e42f((uint8_t)(r >> 16));
  f3 = e42f((uint8_t)(r >> 24));
#endif
}

// ---------------- Threefry-2x32 (JAX-compatible, 20 rounds) ----------------
__host__ __device__ inline void tf2x32(uint32_t k0, uint32_t k1,
                                       uint32_t& x0, uint32_t& x1) {
  const uint32_t ks2 = k0 ^ k1 ^ 0x1BD11BDAu;
#define ROTL32(v, d) (((v) << (d)) | ((v) >> (32 - (d))))
#define TF_RND(r) { x0 += x1; x1 = ROTL32(x1, r); x1 ^= x0; }
  x0 += k0; x1 += k1;
  TF_RND(13) TF_RND(15) TF_RND(26) TF_RND(6)
  x0 += k1;  x1 += ks2 + 1u;
  TF_RND(17) TF_RND(29) TF_RND(16) TF_RND(24)
  x0 += ks2; x1 += k0 + 2u;
  TF_RND(13) TF_RND(15) TF_RND(26) TF_RND(6)
  x0 += k0;  x1 += k1 + 3u;
  TF_RND(17) TF_RND(29) TF_RND(16) TF_RND(24)
  x0 += k1;  x1 += ks2 + 4u;
  TF_RND(13) TF_RND(15) TF_RND(26) TF_RND(6)
  x0 += ks2; x1 += k0 + 5u;
#undef TF_RND
#undef ROTL32
}

__device__ __forceinline__ bool keep_mask(uint32_t k0, uint32_t k1, uint32_t idx) {
  uint32_t x0 = 0u, x1 = idx;
  tf2x32(k0, k1, x0, x1);
  uint32_t bits = x0 ^ x1;
  float u = __uint_as_float((bits >> 9) | 0x3f800000u) - 1.0f;
  return u < KEEPP;
}

// ---------------- CSR build prelude ----------------
__global__ void k_hist(const int* __restrict__ dst, int E, int* __restrict__ counts) {
  int e = blockIdx.x * blockDim.x + threadIdx.x;
  if (e < E) atomicAdd(&counts[dst[e]], 1);
}

// ---- scan stage 1 + dinv + per-graph node counts (batch histogram) ----
__global__ __launch_bounds__(SCAN_B) void k_scan1d(const int* __restrict__ counts,
                                                   int* __restrict__ bsum,
                                                   float* __restrict__ dinv,
                                                   const int* __restrict__ batch,
                                                   float* __restrict__ cnts, int N) {
  __shared__ int lh[NGRAPH];
  if (threadIdx.x < NGRAPH) lh[threadIdx.x] = 0;
  __syncthreads();
  int i = blockIdx.x * SCAN_B + threadIdx.x;
  int v = 0;
  if (i < N) {
    v = counts[i];
    dinv[i] = rsqrtf((float)v + 1.0f);  // in-degree + self-loop
    atomicAdd(&lh[batch[i]], 1);
  }
  int r = v;
  for (int off = 32; off > 0; off >>= 1) r += __shfl_down(r, off);
  __shared__ int ws[4];
  if ((threadIdx.x & 63) == 0) ws[threadIdx.x >> 6] = r;
  __syncthreads();
  if (threadIdx.x == 0) bsum[blockIdx.x] = ws[0] + ws[1] + ws[2] + ws[3];
  if (threadIdx.x < NGRAPH && lh[threadIdx.x] != 0)
    atomicAdd(&cnts[threadIdx.x], (float)lh[threadIdx.x]);
}

// ---------------- W split helper (bf16 hi + residual lo, frag layout) ----------------
__device__ __forceinline__ void wsplit_one(const float* __restrict__ W,
                                           short8* __restrict__ Wh,
                                           short8* __restrict__ Wl, int i) {
  int lane = i & 63, f = i >> 6;
  int kc = f >> 2, ct = f & 3;
  int kbase = kc * 32 + ((lane >> 4) << 3);
  int n = ct * 16 + (lane & 15);
  short8 h, l;
#pragma unroll
  for (int j = 0; j < 8; ++j) {
    float w = W[(size_t)(kbase + j) * HID + n];
    uint32_t u = __float_as_uint(w);
    h[j] = (short)(u >> 16);
    float r = w - __uint_as_float(u & 0xFFFF0000u);
    l[j] = (short)(__float_as_uint(r) >> 16);
  }
  Wh[i] = h;
  Wl[i] = l;
}

// ---- scan stage 2 (block 0, + zero sums) + three W splits (blocks 1..3) ----
__global__ __launch_bounds__(1024) void k_scan2w(const int* __restrict__ bsum,
                                                 int* __restrict__ bpre, int B,
                                                 float* __restrict__ sums,
                                                 const float* __restrict__ W1,
                                                 short8* __restrict__ Wh1, short8* __restrict__ Wl1,
                                                 const float* __restrict__ W2,
                                                 short8* __restrict__ Wh2, short8* __restrict__ Wl2,
                                                 const float* __restrict__ W3,
                                                 short8* __restrict__ Wh3, short8* __restrict__ Wl3) {
  if (blockIdx.x == 0) {
    __shared__ int s[1024];
    int tid = threadIdx.x;
    for (int i = tid; i < NGRAPH * HID; i += 1024) sums[i] = 0.0f;
    int v = (tid < B) ? bsum[tid] : 0;
    s[tid] = v;
    __syncthreads();
    for (int off = 1; off < 1024; off <<= 1) {
      int t = (tid >= off) ? s[tid - off] : 0;
      __syncthreads();
      s[tid] += t;
      __syncthreads();
    }
    if (tid < B) bpre[tid] = s[tid] - v;  // exclusive
    return;
  }
  int b = blockIdx.x - 1;
  int tid = threadIdx.x;
  if (b == 0) {                      // W1: KC=4 -> 1024 entries
    wsplit_one(W1, Wh1, Wl1, tid);
  } else if (b == 1 && tid < 512) {  // W2: KC=2 -> 512 entries
    wsplit_one(W2, Wh2, Wl2, tid);
  } else if (b == 2 && tid < 512) {  // W3
    wsplit_one(W3, Wh3, Wl3, tid);
  }
}

// ---- scan stage 3: local scan + offset -> row_off, cursor ----
__global__ __launch_bounds__(SCAN_B) void k_scan3(const int* __restrict__ counts,
                                                  const int* __restrict__ bpre,
                                                  int* __restrict__ row_off,
                                                  int* __restrict__ cursor,
                                                  int N, int E) {
  __shared__ int s[SCAN_B];
  int tid = threadIdx.x;
  int i = blockIdx.x * SCAN_B + tid;
  int v = (i < N) ? counts[i] : 0;
  s[tid] = v;
  __syncthreads();
  for (int off = 1; off < SCAN_B; off <<= 1) {
    int t = (tid >= off) ? s[tid - off] : 0;
    __syncthreads();
    s[tid] += t;
    __syncthreads();
  }
  if (i < N) {
    int excl = bpre[blockIdx.x] + s[tid] - v;
    row_off[i] = excl;
    cursor[i] = excl;
  }
  if (i == 0) row_off[N] = E;
}

// ---------------- MFMA gemm tile body ----------------
template <int K>
__device__ __forceinline__ void mgemm_tile(const float* __restrict__ A,
                                           const short8* __restrict__ Wh,
                                           const short8* __restrict__ Wl,
                                           uint8_t* __restrict__ C, int N,
                                           int tile) {
  constexpr int KC = K / 32;
  const int lane = threadIdx.x & 63;
  const int wv = threadIdx.x >> 6;
  const int m = lane & 15;
  const int q = lane >> 4;
  const int row0 = tile * 64 + wv * 16;
  if (row0 >= N) return;
  const int arow = min(row0 + m, N - 1);
  const float* __restrict__ ap = A + (size_t)arow * K + (q << 3);

  floatx4 acc[4];
#pragma unroll
  for (int ct = 0; ct < 4; ++ct) acc[ct] = (floatx4){0.f, 0.f, 0.f, 0.f};

#pragma unroll
  for (int kc = 0; kc < KC; ++kc) {
    const floatx4* apv = (const floatx4*)(ap + kc * 32);
    floatx4 x0 = apv[0];
    floatx4 x1 = apv[1];
    short8 ah, al;
#pragma unroll
    for (int j = 0; j < 4; ++j) {
      uint32_t u = __float_as_uint(x0[j]);
      ah[j] = (short)(u >> 16);
      float r = x0[j] - __uint_as_float(u & 0xFFFF0000u);
      al[j] = (short)(__float_as_uint(r) >> 16);
    }
#pragma unroll
    for (int j = 0; j < 4; ++j) {
      uint32_t u = __float_as_uint(x1[j]);
      ah[4 + j] = (short)(u >> 16);
      float r = x1[j] - __uint_as_float(u & 0xFFFF0000u);
      al[4 + j] = (short)(__float_as_uint(r) >> 16);
    }
#pragma unroll
    for (int ct = 0; ct < 4; ++ct) {
      short8 bh = Wh[(kc * 4 + ct) * 64 + lane];
      short8 bl = Wl[(kc * 4 + ct) * 64 + lane];
      acc[ct] = __builtin_amdgcn_mfma_f32_16x16x32_bf16(ah, bh, acc[ct], 0, 0, 0);
      acc[ct] = __builtin_amdgcn_mfma_f32_16x16x32_bf16(ah, bl, acc[ct], 0, 0, 0);
      acc[ct] = __builtin_amdgcn_mfma_f32_16x16x32_bf16(al, bh, acc[ct], 0, 0, 0);
    }
  }

  uint8_t* __restrict__ cp = C + (size_t)row0 * HID;
#pragma unroll
  for (int ct = 0; ct < 4; ++ct)
#pragma unroll
    for (int r = 0; r < 4; ++r) {
      int rr = (q << 2) + r;
      if (row0 + rr < N) cp[(size_t)rr * HID + ct * 16 + m] = f2e4(acc[ct][r]);
    }
}

// ---------------- fused CSR build + MFMA GEMM layer 1 (interleaved) ----------------
template <int K>
__global__ __launch_bounds__(256) void k_mgemm_build(
    const float* __restrict__ A, const short8* __restrict__ Wh,
    const short8* __restrict__ Wl, uint8_t* __restrict__ C, int N,
    const int* __restrict__ src, const int* __restrict__ dst,
    const float* __restrict__ dinv, int* __restrict__ cursor,
    int2* __restrict__ csr, int E, int build_blocks, int gemm_blocks) {
  const long T = (long)build_blocks + gemm_blocks;
  const long b = (long)blockIdx.x;
  const long gb = (b * gemm_blocks) / T;
  const bool is_g = (((b + 1) * gemm_blocks) / T) != gb;
  if (!is_g) {
    int bb = (int)(b - gb);
    int e = bb * 256 + (int)threadIdx.x;
    if (e < E) {
      int s = src[e], d = dst[e];
      int pos = atomicAdd(&cursor[d], 1);
      csr[pos] = make_int2(s, __float_as_int(dinv[s] * dinv[d]));
    }
    return;
  }
  mgemm_tile<K>(A, Wh, Wl, C, N, (int)gb);
}

// ---------------- MFMA GEMM (standalone, layers 2/3) ----------------
template <int K>
__global__ __launch_bounds__(256) void k_mgemm(const float* __restrict__ A,
                                               const short8* __restrict__ Wh,
                                               const short8* __restrict__ Wl,
                                               uint8_t* __restrict__ C, int N) {
  mgemm_tile<K>(A, Wh, Wl, C, N, (int)blockIdx.x);
}

// ---------------- gather core: quarter-wave, packed fp8 decode ----------------
__device__ __forceinline__ float gather_core(const uint8_t* __restrict__ tmp,
                                             const int2* __restrict__ csr,
                                             int beg, int end, int q, int sl) {
  float a0 = 0.f, a1 = 0.f, a2 = 0.f, a3 = 0.f;
  for (int j = beg; j < end; j += 8) {
    int e0 = j + q, e1 = j + 4 + q;
    bool v0 = e0 < end, v1 = e1 < end;
    int2 p0 = csr[v0 ? e0 : beg];
    int2 p1 = csr[v1 ? e1 : beg];
    float w0 = v0 ? __int_as_float(p0.y) : 0.0f;
    float w1 = v1 ? __int_as_float(p1.y) : 0.0f;
    uint32_t r0 = *(const uint32_t*)(tmp + (size_t)p0.x * HID + sl * 4);
    uint32_t r1 = *(const uint32_t*)(tmp + (size_t)p1.x * HID + sl * 4);
    float f0, f1, f2, f3, g0, g1, g2, g3;
    e42f_x4(r0, f0, f1, f2, f3);
    e42f_x4(r1, g0, g1, g2, g3);
    a0 = fmaf(f0, w0, a0); a1 = fmaf(f1, w0, a1);
    a2 = fmaf(f2, w0, a2); a3 = fmaf(f3, w0, a3);
    a0 = fmaf(g0, w1, a0); a1 = fmaf(g1, w1, a1);
    a2 = fmaf(g2, w1, a2); a3 = fmaf(g3, w1, a3);
  }
  a0 += __shfl_xor(a0, 16); a0 += __shfl_xor(a0, 32);
  a1 += __shfl_xor(a1, 16); a1 += __shfl_xor(a1, 32);
  a2 += __shfl_xor(a2, 16); a2 += __shfl_xor(a2, 32);
  a3 += __shfl_xor(a3, 16); a3 += __shfl_xor(a3, 32);
  return (q == 0) ? a0 : (q == 1) ? a1 : (q == 2) ? a2 : a3;
}

// ---------------- gather + self-loop + bias + relu + dropout -> fp32 h ----------------
__global__ __launch_bounds__(256) void k_gather(const uint8_t* __restrict__ tmp,
                                                const int* __restrict__ row_off,
                                                const int2* __restrict__ csr,
                                                const float* __restrict__ dinv,
                                                const float* __restrict__ bias,
                                                float* __restrict__ outh, int N,
                                                uint32_t k0, uint32_t k1) {
  const int node = blockIdx.x * 4 + (threadIdx.x >> 6);
  const int lane = threadIdx.x & 63;
  const int q = lane >> 4;
  const int sl = lane & 15;
  if (node >= N) return;
  const int beg = __builtin_amdgcn_readfirstlane(row_off[node]);
  const int end = __builtin_amdgcn_readfirstlane(row_off[node + 1]);
  float acc = gather_core(tmp, csr, beg, end, q, sl);
  const int ch = sl * 4 + q;
  const float dnode = dinv[node];
  const int idx = node * HID + ch;
  float v = acc + e42f(tmp[(size_t)node * HID + ch]) * dnode * dnode + bias[ch];
  v = fmaxf(v, 0.0f);
  v = keep_mask(k0, k1, (uint32_t)idx) ? v / KEEPP : 0.0f;
  outh[idx] = v;
}

// ---------------- mean-pool partials (LDS-staged; sums only) ----------------
__global__ __launch_bounds__(256) void k_pool(const float* __restrict__ h,
                                              const int* __restrict__ batch,
                                              float* __restrict__ sums, int N) {
  __shared__ float ls[NGRAPH * HID];
  for (int i = threadIdx.x; i < NGRAPH * HID; i += 256) ls[i] = 0.0f;
  __syncthreads();
  const int lane = threadIdx.x & 63;
  const int wave = threadIdx.x >> 6;
  int per = (N + gridDim.x - 1) / gridDim.x;
  int beg = blockIdx.x * per;
  int end = min(N, beg + per);
  for (int i = beg + wave; i < end; i += 4) {
    int g = batch[i];
    atomicAdd(&ls[g * HID + lane], h[(size_t)i * HID + lane]);
  }
  __syncthreads();
  for (int i = threadIdx.x; i < NGRAPH * HID; i += 256)
    if (ls[i] != 0.0f) atomicAdd(&sums[i], ls[i]);
}

// ---------------- MLP head (single block) ----------------
__global__ __launch_bounds__(256) void k_head(const float* __restrict__ sums,
                                              const float* __restrict__ cnts,
                                              const float* __restrict__ Wm1,
                                              const float* __restrict__ bm1,
                                              const float* __restrict__ Wm2,
                                              const float* __restrict__ bm2,
                                              float* __restrict__ out,
                                              uint32_t k0, uint32_t k1) {
  __shared__ float pooled[NGRAPH * HID];
  __shared__ float m[NGRAPH * HID];
  for (int i = threadIdx.x; i < NGRAPH * HID; i += 256) {
    int g = i >> 6;
    pooled[i] = sums[i] / fmaxf(cnts[g], 1.0f);
  }
  __syncthreads();
  for (int i = threadIdx.x; i < NGRAPH * HID; i += 256) {
    int g = i >> 6, j = i & 63;
    float acc = bm1[j];
#pragma unroll 8
    for (int k = 0; k < HID; ++k)
      acc = fmaf(pooled[g * HID + k], Wm1[k * HID + j], acc);
    acc = fmaxf(acc, 0.0f);
    m[i] = keep_mask(k0, k1, (uint32_t)i) ? acc / KEEPP : 0.0f;
  }
  __syncthreads();
  if (threadIdx.x < NGRAPH) {
    int g = threadIdx.x;
    float acc = bm2[0];
#pragma unroll 8
    for (int j = 0; j < HID; ++j)
      acc = fmaf(m[g * HID + j], Wm2[j], acc);
    out[g] = acc;
  }
}

extern "C" void kernel_launch(void* const* d_in, const int* in_sizes, int n_in,
                              void* d_out, int out_size, void* d_ws, size_t ws_size,
                              hipStream_t stream) {
  const float* x     = (const float*)d_in[0];
  const int*   ei    = (const int*)d_in[1];
  const int*   batch = (const int*)d_in[2];
  const float* W1 = (const float*)d_in[3];
  const float* b1 = (const float*)d_in[4];
  const float* W2 = (const float*)d_in[5];
  const float* b2 = (const float*)d_in[6];
  const float* W3 = (const float*)d_in[7];
  const float* b3 = (const float*)d_in[8];
  const float* Wm1 = (const float*)d_in[9];
  const float* bm1 = (const float*)d_in[10];
  const float* Wm2 = (const float*)d_in[11];
  const float* bm2 = (const float*)d_in[12];
  float* out = (float*)d_out;

  const int N = in_sizes[0] / INCH;
  const int E = in_sizes[1] / 2;
  const int* src = ei;
  const int* dst = ei + E;
  const int NB = (N + SCAN_B - 1) / SCAN_B;

  // workspace layout (counts and cnts contiguous -> single memset)
  char* ws = (char*)d_ws;
  size_t off = 0;
  uint8_t* B0 = (uint8_t*)(ws + off); off += (size_t)N * HID;            // fp8 tmp
  off = (off + 15) & ~(size_t)15;
  float* B1      = (float*)(ws + off); off += (size_t)N * HID * 4;       // fp32 h
  int*   counts  = (int*)  (ws + off); off += (size_t)N * 4;
  float* cnts    = (float*)(ws + off); off += NGRAPH * 4;                // zeroed w/ counts
  float* dinv    = (float*)(ws + off); off += (size_t)N * 4;
  int*   row_off = (int*)  (ws + off); off += ((size_t)N + 4) * 4;
  int*   cursor  = (int*)  (ws + off); off += (size_t)N * 4;
  int*   bsum    = (int*)  (ws + off); off += 1024 * 4;
  int*   bpre    = (int*)  (ws + off); off += 1024 * 4;
  int2*  csr     = (int2*) (ws + off); off += (size_t)E * 8;
  float* sums    = (float*)(ws + off); off += NGRAPH * HID * 4;          // zeroed in scan2w
  off = (off + 15) & ~(size_t)15;
  short8* Wh1 = (short8*)(ws + off); off += 1024 * 16;
  short8* Wl1 = (short8*)(ws + off); off += 1024 * 16;
  short8* Wh2 = (short8*)(ws + off); off += 512 * 16;
  short8* Wl2 = (short8*)(ws + off); off += 512 * 16;
  short8* Wh3 = (short8*)(ws + off); off += 512 * 16;
  short8* Wl3 = (short8*)(ws + off); off += 512 * 16;

  // dropout keys: dk[i] = threefry2x32((0,42),(0,i))
  uint32_t dk[4][2];
  for (uint32_t i = 0; i < 4; ++i) {
    uint32_t a = 0u, b = i;
    tf2x32(0u, 42u, a, b);
    dk[i][0] = a; dk[i][1] = b;
  }

  // ---- prelude ----
  hipMemsetAsync(counts, 0, ((size_t)N + NGRAPH) * sizeof(int), stream);
  k_hist<<<(E + 255) / 256, 256, 0, stream>>>(dst, E, counts);
  k_scan1d<<<NB, SCAN_B, 0, stream>>>(counts, bsum, dinv, batch, cnts, N);
  k_scan2w<<<4, 1024, 0, stream>>>(bsum, bpre, NB, sums,
                                   W1, Wh1, Wl1, W2, Wh2, Wl2, W3, Wh3, Wl3);
  k_scan3<<<NB, SCAN_B, 0, stream>>>(counts, bpre, row_off, cursor, N, E);

  const int build_grid = (E + 255) / 256;
  const int mg_grid    = (N + 63) / 64;
  const int gath_grid  = (N + 3) / 4;

  // ---- layer 1 (K=128) GEMM fused with CSR build ----
  k_mgemm_build<INCH><<<build_grid + mg_grid, 256, 0, stream>>>(
      x, Wh1, Wl1, B0, N, src, dst, dinv, cursor, csr, E, build_grid, mg_grid);
  k_gather<<<gath_grid, 256, 0, stream>>>(B0, row_off, csr, dinv, b1,
                                          B1, N, dk[0][0], dk[0][1]);
  // ---- layer 2 (K=64) ----
  k_mgemm<HID><<<mg_grid, 256, 0, stream>>>(B1, Wh2, Wl2, B0, N);
  k_gather<<<gath_grid, 256, 0, stream>>>(B0, row_off, csr, dinv, b2,
                                          B1, N, dk[1][0], dk[1][1]);
  // ---- layer 3 (K=64) ----
  k_mgemm<HID><<<mg_grid, 256, 0, stream>>>(B1, Wh3, Wl3, B0, N);
  k_gather<<<gath_grid, 256, 0, stream>>>(B0, row_off, csr, dinv, b3,
                                          B1, N, dk[2][0], dk[2][1]);

  // ---- pool + head ----
  k_pool<<<256, 256, 0, stream>>>(B1, batch, sums, N);
  k_head<<<1, 256, 0, stream>>>(sums, cnts, Wm1, bm1, Wm2, bm2, out,
                                dk[3][0], dk[3][1]);
  (void)n_in; (void)out_size; (void)ws_size;
}